// Round 7
// baseline (16257.297 us; speedup 1.0000x reference)
//
#include <hip/hip_runtime.h>
#include <stdint.h>

#define B_ 128
#define I_ 2048
#define O_ 2048
#define T_ 100

typedef short bf16x8 __attribute__((ext_vector_type(8)));
typedef float f32x4 __attribute__((ext_vector_type(4)));

// ---------------- ws layout ----------------
#define WT_BYTES  ((size_t)3 * O_ * I_ * 2)          // 25165824
#define ST_BYTES  ((size_t)B_ * T_ * I_ * 2)         // 52428800
#define CUR_OFF   (WT_BYTES + ST_BYTES)              // 77594624
#define CUR_BYTES ((size_t)B_ * T_ * O_ * 4)         // 104857600
#define STATS_OFF (CUR_OFF + CUR_BYTES)              // 182452224
#define WS_NEED   (STATS_OFF + 256)                  // proven: ws_size >= this (round 5)

__device__ __forceinline__ unsigned short f2bf(float x) {
    uint32_t u = __float_as_uint(x);
    uint32_t r = (u + 0x7fffu + ((u >> 16) & 1u)) >> 16;   // RNE
    return (unsigned short)r;
}
__device__ __forceinline__ float bf2f(unsigned short h) {
    return __uint_as_float(((uint32_t)h) << 16);
}

__device__ __forceinline__ void delay_us(unsigned long long us) {
    long long ticks = (long long)(us * 100ull);     // wall clock ~100 MHz
    long long t0 = wall_clock64();
    for (long long i = 0; i < 50000000LL; ++i) {
        if (wall_clock64() - t0 >= ticks) break;
        __builtin_amdgcn_s_sleep(8);
    }
}

// ---------------- prep 1: weight -> 3 bf16 planes, transposed [o][i] ----------------
__global__ void prep_w(const float* __restrict__ W, unsigned short* __restrict__ Wt) {
    __shared__ float tile[64][65];
    const int tid = threadIdx.x;
    const int ib = (blockIdx.x & 31) * 64;
    const int ob = (blockIdx.x >> 5) * 64;
#pragma unroll
    for (int k = 0; k < 4; ++k) {
        int flat4 = k * 256 + tid;
        int row = flat4 >> 4, c4 = flat4 & 15;
        float4 v = *(const float4*)&W[(size_t)(ib + row) * O_ + ob + c4 * 4];
        tile[row][c4 * 4 + 0] = v.x; tile[row][c4 * 4 + 1] = v.y;
        tile[row][c4 * 4 + 2] = v.z; tile[row][c4 * 4 + 3] = v.w;
    }
    __syncthreads();
#pragma unroll
    for (int k = 0; k < 4; ++k) {
        int flat = k * 256 + tid;
        int o = flat >> 4, i4 = flat & 15;
        unsigned short h[3][4];
#pragma unroll
        for (int jj = 0; jj < 4; ++jj) {
            float wv = tile[i4 * 4 + jj][o];
            unsigned short h0 = f2bf(wv); float r = wv - bf2f(h0);
            unsigned short h1 = f2bf(r);  r = r - bf2f(h1);
            unsigned short h2 = f2bf(r);
            h[0][jj] = h0; h[1][jj] = h1; h[2][jj] = h2;
        }
        size_t base = (size_t)(ob + o) * I_ + ib + i4 * 4;
#pragma unroll
        for (int p = 0; p < 3; ++p) {
            ushort4 v4 = make_ushort4(h[p][0], h[p][1], h[p][2], h[p][3]);
            *(ushort4*)(Wt + (size_t)p * O_ * I_ + base) = v4;
        }
    }
}

// ---------------- prep 2: spike -> bf16, transposed [b][t][i] ----------------
__global__ void prep_s(const float* __restrict__ S, unsigned short* __restrict__ St) {
    __shared__ float tile[128][101];
    const int tid = threadIdx.x;
    const int b  = blockIdx.x >> 4;
    const int ib = (blockIdx.x & 15) * 128;
    for (int k = 0; k < 13; ++k) {
        int flat4 = k * 256 + tid;
        if (flat4 < 3200) {
            int row = flat4 / 25, c4 = flat4 % 25;
            float4 v = *(const float4*)&S[((size_t)b * I_ + ib + row) * T_ + c4 * 4];
            tile[row][c4 * 4 + 0] = v.x; tile[row][c4 * 4 + 1] = v.y;
            tile[row][c4 * 4 + 2] = v.z; tile[row][c4 * 4 + 3] = v.w;
        }
    }
    __syncthreads();
    for (int k = 0; k < 13; ++k) {
        int flat = k * 256 + tid;
        if (flat < 3200) {
            int t = flat >> 5, i4 = flat & 31;
            ushort4 v;
            v.x = f2bf(tile[i4 * 4 + 0][t]); v.y = f2bf(tile[i4 * 4 + 1][t]);
            v.z = f2bf(tile[i4 * 4 + 2][t]); v.w = f2bf(tile[i4 * 4 + 3][t]);
            *(ushort4*)(St + ((size_t)b * T_ + t) * I_ + ib + i4 * 4) = v;
        }
    }
}

// ---------------- MFMA GEMM (device under test), currents -> ws ----------------
__device__ __forceinline__ void compute_tile(const char* smem, int lane, int w,
                                             f32x4 acc[7][2]) {
    const int c = lane & 15, kg = lane >> 4;
    bf16x8 a[7];
#pragma unroll
    for (int mt = 0; mt < 7; ++mt) {
        int R = mt * 16 + c;
        a[mt] = *(const bf16x8*)(smem + R * 64 + ((kg ^ ((R >> 1) & 3)) * 16));
    }
#pragma unroll
    for (int p = 0; p < 3; ++p) {
#pragma unroll
        for (int nt = 0; nt < 2; ++nt) {
            int R = w * 32 + nt * 16 + c;
            bf16x8 bv = *(const bf16x8*)(smem + 7168 + p * 16384 + R * 64 +
                                         ((kg ^ ((R >> 1) & 3)) * 16));
#pragma unroll
            for (int mt = 0; mt < 7; ++mt)
                acc[mt][nt] = __builtin_amdgcn_mfma_f32_16x16x32_bf16(
                    a[mt], bv, acc[mt][nt], 0, 0, 0);
        }
    }
}

__launch_bounds__(512, 2)
__global__ void gemm_cur(const unsigned short* __restrict__ Wt_,
                         const unsigned short* __restrict__ St_,
                         float* __restrict__ CUR) {
    __shared__ f32x4 smem4[56320 / 16];
    char* smem = (char*)smem4;
    const char* Wt = (const char*)Wt_;
    const char* St = (const char*)St_;
    const int tid = threadIdx.x, lane = tid & 63, w = tid >> 6;

    const int bid = blockIdx.x;
    const int x = bid & 7, j = bid >> 3;
    const int oc = j >> 4;
    const int b  = x * 16 + (j & 15);
    const int o0 = oc * 256;

    f32x4 acc[7][2];
#pragma unroll
    for (int mt = 0; mt < 7; ++mt)
#pragma unroll
        for (int nt = 0; nt < 2; ++nt)
            acc[mt][nt] = (f32x4){0.f, 0.f, 0.f, 0.f};

    if (tid < 48) *(f32x4*)(smem + 6400 + tid * 16) = (f32x4){0.f, 0.f, 0.f, 0.f};

    const size_t I2 = I_ * 2;
    const size_t PLANE = (size_t)O_ * I_ * 2;

    for (int kt = 0; kt < 64; ++kt) {
        __syncthreads();
        if (tid < 400) {
            int r = tid >> 2, kc = tid & 3;
            f32x4 v = *(const f32x4*)(St + ((size_t)b * T_ + r) * I2 + kt * 64 + kc * 16);
            *(f32x4*)(smem + r * 64 + ((kc ^ ((r >> 1) & 3)) * 16)) = v;
        }
#pragma unroll
        for (int s = 0; s < 6; ++s) {
            int q = s * 512 + tid;
            int r = q >> 2, kc = q & 3;
            int p = r >> 8, ol = r & 255;
            f32x4 v = *(const f32x4*)(Wt + (size_t)p * PLANE +
                                      (size_t)(o0 + ol) * I2 + kt * 64 + kc * 16);
            *(f32x4*)(smem + 7168 + p * 16384 + ol * 64 +
                      ((kc ^ ((ol >> 1) & 3)) * 16)) = v;
        }
        __syncthreads();
        compute_tile(smem, lane, w, acc);
    }

    const int c = lane & 15, kg = lane >> 4;
#pragma unroll
    for (int mt = 0; mt < 7; ++mt)
#pragma unroll
        for (int nt = 0; nt < 2; ++nt)
#pragma unroll
            for (int r = 0; r < 4; ++r) {
                int t = mt * 16 + kg * 4 + r;
                if (t < T_)
                    CUR[((size_t)b * T_ + t) * O_ + o0 + w * 32 + nt * 16 + c] =
                        acc[mt][nt][r];
            }
}

// ---------------- cmp_write: VALU GEMM (known-good) writes OUTPUT + dual-scan stats --
#define TI 32
#define TO 256
__launch_bounds__(256, 3)
__global__ void cmp_write(const float* __restrict__ spike,
                          const float* __restrict__ weight,
                          const float* __restrict__ CUR,
                          float* __restrict__ out,
                          unsigned* __restrict__ stats) {
    __shared__ float Wlds[TI][TO];
    __shared__ float Slds[TI][128];
    __shared__ float m_buf[TO];
    __shared__ float m_buf2[TO];
    const int tid = threadIdx.x;
    const int lane = tid & 63;
    const int tq = tid >> 6;
    const int b = blockIdx.x >> 3;
    const int oc = blockIdx.x & 7;
    const int o0 = oc * TO;
    float4 acc[25];
#pragma unroll
    for (int t = 0; t < 25; ++t) acc[t] = make_float4(0.f, 0.f, 0.f, 0.f);
    const float4* Wf4 = (const float4*)weight;
    for (int it = 0; it < I_ / TI; ++it) {
        const int i0 = it * TI;
        __syncthreads();
#pragma unroll
        for (int k = 0; k < 8; ++k) {
            int flat4 = k * 256 + tid;
            int i_l = flat4 >> 6, o4 = flat4 & 63;
            float4 v = Wf4[(size_t)(i0 + i_l) * (O_ / 4) + (o0 >> 2) + o4];
            ((float4*)Wlds)[i_l * (TO / 4) + o4] = v;
        }
#pragma unroll
        for (int k = 0; k < 13; ++k) {
            int flat = k * 256 + tid;
            if (flat < TI * T_) {
                int i_l = flat / T_, t = flat - i_l * T_;
                int q = t / 25, tt = t - q * 25;
                Slds[i_l][q * 32 + tt] = spike[((size_t)b * I_ + i0 + i_l) * T_ + t];
            }
        }
        __syncthreads();
        for (int i_l = 0; i_l < TI; ++i_l) {
            float4 wv = ((const float4*)Wlds)[i_l * (TO / 4) + lane];
            const float* srow = &Slds[i_l][tq * 32];
#pragma unroll
            for (int v = 0; v < 6; ++v) {
                float4 sv = ((const float4*)srow)[v];
                acc[v*4+0].x = fmaf(wv.x, sv.x, acc[v*4+0].x); acc[v*4+0].y = fmaf(wv.y, sv.x, acc[v*4+0].y);
                acc[v*4+0].z = fmaf(wv.z, sv.x, acc[v*4+0].z); acc[v*4+0].w = fmaf(wv.w, sv.x, acc[v*4+0].w);
                acc[v*4+1].x = fmaf(wv.x, sv.y, acc[v*4+1].x); acc[v*4+1].y = fmaf(wv.y, sv.y, acc[v*4+1].y);
                acc[v*4+1].z = fmaf(wv.z, sv.y, acc[v*4+1].z); acc[v*4+1].w = fmaf(wv.w, sv.y, acc[v*4+1].w);
                acc[v*4+2].x = fmaf(wv.x, sv.z, acc[v*4+2].x); acc[v*4+2].y = fmaf(wv.y, sv.z, acc[v*4+2].y);
                acc[v*4+2].z = fmaf(wv.z, sv.z, acc[v*4+2].z); acc[v*4+2].w = fmaf(wv.w, sv.z, acc[v*4+2].w);
                acc[v*4+3].x = fmaf(wv.x, sv.w, acc[v*4+3].x); acc[v*4+3].y = fmaf(wv.y, sv.w, acc[v*4+3].y);
                acc[v*4+3].z = fmaf(wv.z, sv.w, acc[v*4+3].z); acc[v*4+3].w = fmaf(wv.w, sv.w, acc[v*4+3].w);
            }
            float s24 = srow[24];
            acc[24].x = fmaf(wv.x, s24, acc[24].x); acc[24].y = fmaf(wv.y, s24, acc[24].y);
            acc[24].z = fmaf(wv.z, s24, acc[24].z); acc[24].w = fmaf(wv.w, s24, acc[24].w);
        }
    }
    __syncthreads();
    unsigned cnt_dec = 0, cnt_st = 0;
    int minF = 0x7FFFFFFF;
    for (int r = 0; r < 4; ++r) {
        if (tq == r) {
#pragma unroll
            for (int jj = 0; jj < 4; ++jj) {
                const int ol = lane * 4 + jj;
                const int o = o0 + ol;
                float mv = (r == 0) ? 0.f : m_buf[ol];
                float mm = (r == 0) ? 0.f : m_buf2[ol];
                float* orow = out + ((size_t)b * O_ + o) * T_ + r * 25;
                for (int tl = 0; tl < 25; ++tl) {
                    int t = r * 25 + tl;
                    float cv = (jj == 0) ? acc[tl].x : (jj == 1) ? acc[tl].y
                             : (jj == 2) ? acc[tl].z : acc[tl].w;
                    float cm = CUR[((size_t)b * T_ + t) * O_ + o];
                    mv += cv; bool fv = (mv > 1.0f);
                    orow[tl] = fv ? 1.0f : 0.0f;             // OUTPUT = VALU path
                    mv = fv ? 0.f : mv;
                    mm += cm; bool fm = (mm > 1.0f); mm = fm ? 0.f : mm;
                    if (fv != fm) {
                        ++cnt_dec;
                        int fl = (b * O_ + o) * T_ + t;
                        if (fl < minF) minF = fl;
                    }
                    if (fabsf(cv - cm) > 1e-3f) ++cnt_st;
                }
                m_buf[ol] = mv; m_buf2[ol] = mm;
            }
        }
        __syncthreads();
    }
    if (cnt_dec) { atomicAdd(&stats[0], cnt_dec); atomicMin((int*)&stats[1], minF); }
    if (cnt_st)  atomicAdd(&stats[2], cnt_st);
}

// ---------------- stats init + duration-encoded diagnosis (3 channels) ----------------
__global__ void init_stats(unsigned* stats) {
    stats[0] = 0u; stats[1] = 0x7FFFFFFFu; stats[2] = 0u;
}

// dur = 3000 + 1000*ceil_log2(M) + 40*ceil_log2(S), each capped at 15
__global__ void diag_ms(const unsigned* __restrict__ stats) {
    unsigned M = stats[0], S = stats[2];
    unsigned Ld = 0, mm = (M > 0xFFFFFu) ? 0xFFFFFu : M;
    while (mm) { ++Ld; mm >>= 1; }
    if (Ld > 15u) Ld = 15u;
    unsigned Ls = 0, ss = (S > 0xFFFFFu) ? 0xFFFFFu : S;
    while (ss) { ++Ls; ss >>= 1; }
    if (Ls > 15u) Ls = 15u;
    delay_us(3000ull + 1000ull * Ld + 40ull * Ls);
}

// dur = 2700 + 40*(o_of_first_flip mod 256)   [localizes (w, nt, c)]
__global__ void diag_o(const unsigned* __restrict__ stats) {
    unsigned M = stats[0], F = stats[1];
    unsigned ol = (M && F != 0x7FFFFFFFu) ? ((F / 100u) & 255u) : 0u;
    delay_us(2700ull + 40ull * ol);
}

// dur = 2600 + 40*(t_of_first_flip)           [localizes (mt, kg, r)]
__global__ void diag_t(const unsigned* __restrict__ stats) {
    unsigned M = stats[0], F = stats[1];
    unsigned tt = (M && F != 0x7FFFFFFFu) ? (F % 100u) : 0u;
    delay_us(2600ull + 40ull * tt);
}

// ---------------- fallback (round-1 kernel, known-correct) ----------------
__launch_bounds__(256, 3)
__global__ void lif_fused_kernel(const float* __restrict__ spike,
                                 const float* __restrict__ weight,
                                 float* __restrict__ out) {
    __shared__ float Wlds[TI][TO];
    __shared__ float Slds[TI][128];
    __shared__ float m_buf[TO];
    const int tid = threadIdx.x;
    const int lane = tid & 63;
    const int tq = tid >> 6;
    const int b = blockIdx.x >> 3;
    const int oc = blockIdx.x & 7;
    const int o0 = oc * TO;
    float4 acc[25];
#pragma unroll
    for (int t = 0; t < 25; ++t) acc[t] = make_float4(0.f, 0.f, 0.f, 0.f);
    const float4* Wf4 = (const float4*)weight;
    for (int it = 0; it < I_ / TI; ++it) {
        const int i0 = it * TI;
        __syncthreads();
#pragma unroll
        for (int k = 0; k < 8; ++k) {
            int flat4 = k * 256 + tid;
            int i_l = flat4 >> 6, o4 = flat4 & 63;
            float4 v = Wf4[(size_t)(i0 + i_l) * (O_ / 4) + (o0 >> 2) + o4];
            ((float4*)Wlds)[i_l * (TO / 4) + o4] = v;
        }
#pragma unroll
        for (int k = 0; k < 13; ++k) {
            int flat = k * 256 + tid;
            if (flat < TI * T_) {
                int i_l = flat / T_, t = flat - i_l * T_;
                int q = t / 25, tt = t - q * 25;
                Slds[i_l][q * 32 + tt] = spike[((size_t)b * I_ + i0 + i_l) * T_ + t];
            }
        }
        __syncthreads();
        for (int i_l = 0; i_l < TI; ++i_l) {
            float4 wv = ((const float4*)Wlds)[i_l * (TO / 4) + lane];
            const float* srow = &Slds[i_l][tq * 32];
#pragma unroll
            for (int v = 0; v < 6; ++v) {
                float4 sv = ((const float4*)srow)[v];
                acc[v*4+0].x = fmaf(wv.x, sv.x, acc[v*4+0].x); acc[v*4+0].y = fmaf(wv.y, sv.x, acc[v*4+0].y);
                acc[v*4+0].z = fmaf(wv.z, sv.x, acc[v*4+0].z); acc[v*4+0].w = fmaf(wv.w, sv.x, acc[v*4+0].w);
                acc[v*4+1].x = fmaf(wv.x, sv.y, acc[v*4+1].x); acc[v*4+1].y = fmaf(wv.y, sv.y, acc[v*4+1].y);
                acc[v*4+1].z = fmaf(wv.z, sv.y, acc[v*4+1].z); acc[v*4+1].w = fmaf(wv.w, sv.y, acc[v*4+1].w);
                acc[v*4+2].x = fmaf(wv.x, sv.z, acc[v*4+2].x); acc[v*4+2].y = fmaf(wv.y, sv.z, acc[v*4+2].y);
                acc[v*4+2].z = fmaf(wv.z, sv.z, acc[v*4+2].z); acc[v*4+2].w = fmaf(wv.w, sv.z, acc[v*4+2].w);
                acc[v*4+3].x = fmaf(wv.x, sv.w, acc[v*4+3].x); acc[v*4+3].y = fmaf(wv.y, sv.w, acc[v*4+3].y);
                acc[v*4+3].z = fmaf(wv.z, sv.w, acc[v*4+3].z); acc[v*4+3].w = fmaf(wv.w, sv.w, acc[v*4+3].w);
            }
            float s24 = srow[24];
            acc[24].x = fmaf(wv.x, s24, acc[24].x); acc[24].y = fmaf(wv.y, s24, acc[24].y);
            acc[24].z = fmaf(wv.z, s24, acc[24].z); acc[24].w = fmaf(wv.w, s24, acc[24].w);
        }
    }
    __syncthreads();
    for (int r = 0; r < 4; ++r) {
        if (tq == r) {
#pragma unroll
            for (int jj = 0; jj < 4; ++jj) {
                const int ol = lane * 4 + jj;
                float m = (r == 0) ? 0.0f : m_buf[ol];
                float* orow = out + ((size_t)b * O_ + o0 + ol) * T_ + r * 25;
#pragma unroll
                for (int t = 0; t < 25; ++t) {
                    float cu = (jj == 0) ? acc[t].x : (jj == 1) ? acc[t].y
                             : (jj == 2) ? acc[t].z : acc[t].w;
                    m += cu;
                    bool f = (m > 1.0f);
                    orow[t] = f ? 1.0f : 0.0f;
                    m = f ? 0.0f : m;
                }
                m_buf[ol] = m;
            }
        }
        __syncthreads();
    }
}

extern "C" void kernel_launch(void* const* d_in, const int* in_sizes, int n_in,
                              void* d_out, int out_size, void* d_ws, size_t ws_size,
                              hipStream_t stream) {
    const float* spike  = (const float*)d_in[0];   // [128][2048][100]
    const float* weight = (const float*)d_in[1];   // [2048][2048]
    float* out = (float*)d_out;                    // [128][2048][100]

    if (ws_size < WS_NEED) {
        lif_fused_kernel<<<dim3(B_ * (O_ / TO)), dim3(256), 0, stream>>>(spike, weight, out);
        return;
    }
    unsigned short* Wt = (unsigned short*)d_ws;
    unsigned short* St = (unsigned short*)((char*)d_ws + WT_BYTES);
    float* CUR = (float*)((char*)d_ws + CUR_OFF);
    unsigned* stats = (unsigned*)((char*)d_ws + STATS_OFF);

    init_stats<<<dim3(1), dim3(64), 0, stream>>>(stats);
    prep_w<<<dim3((I_ / 64) * (O_ / 64)), dim3(256), 0, stream>>>(weight, Wt);
    prep_s<<<dim3(B_ * (I_ / 128)), dim3(256), 0, stream>>>(spike, St);
    gemm_cur<<<dim3(B_ * (O_ / 256)), dim3(512), 0, stream>>>(Wt, St, CUR);
    cmp_write<<<dim3(B_ * (O_ / TO)), dim3(256), 0, stream>>>(spike, weight, CUR, out, stats);
    diag_ms<<<dim3(1), dim3(64), 0, stream>>>(stats);
    diag_o<<<dim3(1), dim3(64), 0, stream>>>(stats);
    diag_t<<<dim3(1), dim3(64), 0, stream>>>(stats);
}

// Round 8
// 602.454 us; speedup vs baseline: 26.9851x; 26.9851x over previous
//
#include <hip/hip_runtime.h>
#include <stdint.h>

#define B_ 128
#define I_ 2048
#define O_ 2048
#define T_ 100
#define TAU 2e-4f

typedef short bf16x8 __attribute__((ext_vector_type(8)));
typedef float f32x4 __attribute__((ext_vector_type(4)));

// ---------------- ws layout ----------------
#define WT_BYTES  ((size_t)3 * O_ * I_ * 2)          // 25165824
#define ST_BYTES  ((size_t)B_ * T_ * I_ * 2)         // 52428800
#define CNT_OFF   (WT_BYTES + ST_BYTES)              // 77594624
#define WL_OFF    (CNT_OFF + 256)
#define WL_MAX    ((size_t)B_ * O_)                  // 262144 rows max
#define WS_NEED   (WL_OFF + WL_MAX * 4)

__device__ __forceinline__ unsigned short f2bf(float x) {
    uint32_t u = __float_as_uint(x);
    uint32_t r = (u + 0x7fffu + ((u >> 16) & 1u)) >> 16;   // RNE
    return (unsigned short)r;
}
__device__ __forceinline__ float bf2f(unsigned short h) {
    return __uint_as_float(((uint32_t)h) << 16);
}

__global__ void init_cnt(unsigned* cnt) { if (threadIdx.x == 0) cnt[0] = 0u; }

// ---------------- prep 1: weight -> 3 bf16 planes, transposed [o][i] (proven) -------
__global__ void prep_w(const float* __restrict__ W, unsigned short* __restrict__ Wt) {
    __shared__ float tile[64][65];
    const int tid = threadIdx.x;
    const int ib = (blockIdx.x & 31) * 64;
    const int ob = (blockIdx.x >> 5) * 64;
#pragma unroll
    for (int k = 0; k < 4; ++k) {
        int flat4 = k * 256 + tid;
        int row = flat4 >> 4, c4 = flat4 & 15;
        float4 v = *(const float4*)&W[(size_t)(ib + row) * O_ + ob + c4 * 4];
        tile[row][c4 * 4 + 0] = v.x; tile[row][c4 * 4 + 1] = v.y;
        tile[row][c4 * 4 + 2] = v.z; tile[row][c4 * 4 + 3] = v.w;
    }
    __syncthreads();
#pragma unroll
    for (int k = 0; k < 4; ++k) {
        int flat = k * 256 + tid;
        int o = flat >> 4, i4 = flat & 15;
        unsigned short h[3][4];
#pragma unroll
        for (int jj = 0; jj < 4; ++jj) {
            float wv = tile[i4 * 4 + jj][o];
            unsigned short h0 = f2bf(wv); float r = wv - bf2f(h0);
            unsigned short h1 = f2bf(r);  r = r - bf2f(h1);
            unsigned short h2 = f2bf(r);          // exact 3-split: w = h0+h1+h2
            h[0][jj] = h0; h[1][jj] = h1; h[2][jj] = h2;
        }
        size_t base = (size_t)(ob + o) * I_ + ib + i4 * 4;
#pragma unroll
        for (int p = 0; p < 3; ++p) {
            ushort4 v4 = make_ushort4(h[p][0], h[p][1], h[p][2], h[p][3]);
            *(ushort4*)(Wt + (size_t)p * O_ * I_ + base) = v4;
        }
    }
}

// ---------------- prep 2: spike -> bf16, transposed [b][t][i] (proven) --------------
__global__ void prep_s(const float* __restrict__ S, unsigned short* __restrict__ St) {
    __shared__ float tile[128][101];
    const int tid = threadIdx.x;
    const int b  = blockIdx.x >> 4;
    const int ib = (blockIdx.x & 15) * 128;
    for (int k = 0; k < 13; ++k) {
        int flat4 = k * 256 + tid;
        if (flat4 < 3200) {
            int row = flat4 / 25, c4 = flat4 % 25;
            float4 v = *(const float4*)&S[((size_t)b * I_ + ib + row) * T_ + c4 * 4];
            tile[row][c4 * 4 + 0] = v.x; tile[row][c4 * 4 + 1] = v.y;
            tile[row][c4 * 4 + 2] = v.z; tile[row][c4 * 4 + 3] = v.w;
        }
    }
    __syncthreads();
    for (int k = 0; k < 13; ++k) {
        int flat = k * 256 + tid;
        if (flat < 3200) {
            int t = flat >> 5, i4 = flat & 31;
            ushort4 v;
            v.x = f2bf(tile[i4 * 4 + 0][t]); v.y = f2bf(tile[i4 * 4 + 1][t]);
            v.z = f2bf(tile[i4 * 4 + 2][t]); v.w = f2bf(tile[i4 * 4 + 3][t]);
            *(ushort4*)(St + ((size_t)b * T_ + t) * I_ + ib + i4 * 4) = v;
        }
    }
}

// ---------------- fused MFMA GEMM + LIF scan + borderline flag ----------------------
// Round-3 structure (core proven by round-7 bisect: M=1, structural S clean).
// Block 512 thr = 8 waves. Tile 1 b x 256 o, M=112 (100 t + 12 zero pad), BK=32.
__device__ __forceinline__ void compute_tile(const char* smem, int lane, int w,
                                             f32x4 acc[7][2]) {
    const int c = lane & 15, kg = lane >> 4;
    bf16x8 a[7];
#pragma unroll
    for (int mt = 0; mt < 7; ++mt) {
        int R = mt * 16 + c;
        a[mt] = *(const bf16x8*)(smem + R * 64 + ((kg ^ ((R >> 1) & 3)) * 16));
    }
#pragma unroll
    for (int p = 0; p < 3; ++p) {
#pragma unroll
        for (int nt = 0; nt < 2; ++nt) {
            int R = w * 32 + nt * 16 + c;
            bf16x8 bv = *(const bf16x8*)(smem + 7168 + p * 16384 + R * 64 +
                                         ((kg ^ ((R >> 1) & 3)) * 16));
#pragma unroll
            for (int mt = 0; mt < 7; ++mt)
                acc[mt][nt] = __builtin_amdgcn_mfma_f32_16x16x32_bf16(
                    a[mt], bv, acc[mt][nt], 0, 0, 0);
        }
    }
}

__launch_bounds__(512, 4)
__global__ void lif_mfma3(const unsigned short* __restrict__ Wt_,
                          const unsigned short* __restrict__ St_,
                          float* __restrict__ out,
                          unsigned* __restrict__ cnt,
                          unsigned* __restrict__ wl) {
    __shared__ f32x4 smem4[59392 / 16];
    char* smem = (char*)smem4;
    const char* Wt = (const char*)Wt_;
    const char* St = (const char*)St_;
    const int tid = threadIdx.x, lane = tid & 63, w = tid >> 6;

    // bijective XCD-aware swizzle: XCD x gets b in [x*16, x*16+16)
    const int bid = blockIdx.x;
    const int x = bid & 7, j = bid >> 3;
    const int oc = j >> 4;
    const int b  = x * 16 + (j & 15);
    const int o0 = oc * 256;

    f32x4 acc[7][2];
#pragma unroll
    for (int mt = 0; mt < 7; ++mt)
#pragma unroll
        for (int nt = 0; nt < 2; ++nt)
            acc[mt][nt] = (f32x4){0.f, 0.f, 0.f, 0.f};

    // zero A pad rows (t=100..111), full rows -> swizzle-invariant
    if (tid < 48) *(f32x4*)(smem + 6400 + tid * 16) = (f32x4){0.f, 0.f, 0.f, 0.f};

    const size_t I2 = I_ * 2;
    const size_t PLANE = (size_t)O_ * I_ * 2;

    for (int kt = 0; kt < 64; ++kt) {
        __syncthreads();
        if (tid < 400) {                      // stage A: 100 rows x 4 chunks
            int r = tid >> 2, kc = tid & 3;
            f32x4 v = *(const f32x4*)(St + ((size_t)b * T_ + r) * I2 + kt * 64 + kc * 16);
            *(f32x4*)(smem + r * 64 + ((kc ^ ((r >> 1) & 3)) * 16)) = v;
        }
#pragma unroll
        for (int s = 0; s < 6; ++s) {         // stage B: 3 planes x 256 rows x 4
            int q = s * 512 + tid;
            int r = q >> 2, kc = q & 3;
            int p = r >> 8, ol = r & 255;
            f32x4 v = *(const f32x4*)(Wt + (size_t)p * PLANE +
                                      (size_t)(o0 + ol) * I2 + kt * 64 + kc * 16);
            *(f32x4*)(smem + 7168 + p * 16384 + ol * 64 +
                      ((kc ^ ((ol >> 1) & 3)) * 16)) = v;
        }
        __syncthreads();
        compute_tile(smem, lane, w, acc);
    }
    __syncthreads();

    // epilogue: 2 phases of 128 o; per-wave [32 o][116 t] f32 slice in LDS
    const int c = lane & 15, kg = lane >> 4;
    for (int ph = 0; ph < 2; ++ph) {
        if ((w >> 2) == ph) {
            float* Cw = (float*)(smem + (w & 3) * 14848);
#pragma unroll
            for (int mt = 0; mt < 7; ++mt)
#pragma unroll
                for (int nt = 0; nt < 2; ++nt)
#pragma unroll
                    for (int r = 0; r < 4; ++r)
                        Cw[(nt * 16 + c) * 116 + mt * 16 + kg * 4 + r] = acc[mt][nt][r];
        }
        __syncthreads();
        if ((w >> 2) == ph && lane < 32) {    // sequential LIF scan + borderline flag
            float* row = (float*)(smem + (w & 3) * 14848) + lane * 116;
            float m = 0.f;
            bool flag = false;
            for (int t = 0; t < T_; ++t) {
                m += row[t];
                float d = m - 1.0f;
                flag |= (fabsf(d) < TAU);
                bool f = d > 0.0f;             // strict m > 1, matches reference
                row[t] = f ? 1.0f : 0.0f;
                m = f ? 0.0f : m;
            }
            if (flag) {
                unsigned o = (unsigned)(o0 + ph * 128 + (w & 3) * 32 + lane);
                unsigned idx = atomicAdd(cnt, 1u);
                wl[idx] = ((unsigned)b << 11) | o;
            }
        }
        __syncthreads();
        float* ob = out + ((size_t)b * O_ + o0 + ph * 128) * T_;
        for (int k = 0; k < 7; ++k) {
            int f4 = k * 512 + tid;            // 128 o x 25 float4
            if (f4 < 3200) {
                int o = f4 / 25, t4 = f4 % 25;
                f32x4 v = *(const f32x4*)((const float*)(smem + (o >> 5) * 14848) +
                                          (o & 31) * 116 + t4 * 4);
                *(f32x4*)(ob + (size_t)o * T_ + t4 * 4) = v;
            }
        }
        __syncthreads();
    }
}

// ---------------- fixup: recompute flagged rows, bitwise = np (ascending-i fmaf) ----
__launch_bounds__(256, 2)
__global__ void fixup(const float* __restrict__ spike,
                      const float* __restrict__ W,
                      float* __restrict__ out,
                      const unsigned* __restrict__ cnt,
                      const unsigned* __restrict__ wl) {
    __shared__ float Wcol[I_];
    __shared__ float cbuf[T_];
    const unsigned n = cnt[0];
    for (unsigned ri = blockIdx.x; ri < n; ri += gridDim.x) {
        unsigned e = wl[ri];
        const int b = (int)(e >> 11), o = (int)(e & 2047u);
#pragma unroll
        for (int k = 0; k < 8; ++k)
            Wcol[k * 256 + threadIdx.x] = W[(size_t)(k * 256 + threadIdx.x) * O_ + o];
        __syncthreads();
        const int t = threadIdx.x;
        if (t < T_) {
            float c = 0.f;
            const float* srow = spike + (size_t)b * I_ * T_ + t;
            for (int i = 0; i < I_; ++i)
                c = fmaf(Wcol[i], srow[(size_t)i * T_], c);   // ascending i, single acc
            cbuf[t] = c;
        }
        __syncthreads();
        if (threadIdx.x == 0) {
            float m = 0.f;
            float* orow = out + ((size_t)b * O_ + o) * T_;
            for (int t2 = 0; t2 < T_; ++t2) {
                m += cbuf[t2];
                bool f = m > 1.0f;
                orow[t2] = f ? 1.0f : 0.0f;
                m = f ? 0.0f : m;
            }
        }
        __syncthreads();
    }
}

// ---------------- fallback (round-1 kernel, known-correct) ----------------
#define TI 32
#define TO 256
__launch_bounds__(256, 3)
__global__ void lif_fused_kernel(const float* __restrict__ spike,
                                 const float* __restrict__ weight,
                                 float* __restrict__ out) {
    __shared__ float Wlds[TI][TO];
    __shared__ float Slds[TI][128];
    __shared__ float m_buf[TO];
    const int tid = threadIdx.x;
    const int lane = tid & 63;
    const int tq = tid >> 6;
    const int b = blockIdx.x >> 3;
    const int oc = blockIdx.x & 7;
    const int o0 = oc * TO;
    float4 acc[25];
#pragma unroll
    for (int t = 0; t < 25; ++t) acc[t] = make_float4(0.f, 0.f, 0.f, 0.f);
    const float4* Wf4 = (const float4*)weight;
    for (int it = 0; it < I_ / TI; ++it) {
        const int i0 = it * TI;
        __syncthreads();
#pragma unroll
        for (int k = 0; k < 8; ++k) {
            int flat4 = k * 256 + tid;
            int i_l = flat4 >> 6, o4 = flat4 & 63;
            float4 v = Wf4[(size_t)(i0 + i_l) * (O_ / 4) + (o0 >> 2) + o4];
            ((float4*)Wlds)[i_l * (TO / 4) + o4] = v;
        }
#pragma unroll
        for (int k = 0; k < 13; ++k) {
            int flat = k * 256 + tid;
            if (flat < TI * T_) {
                int i_l = flat / T_, t = flat - i_l * T_;
                int q = t / 25, tt = t - q * 25;
                Slds[i_l][q * 32 + tt] = spike[((size_t)b * I_ + i0 + i_l) * T_ + t];
            }
        }
        __syncthreads();
        for (int i_l = 0; i_l < TI; ++i_l) {
            float4 wv = ((const float4*)Wlds)[i_l * (TO / 4) + lane];
            const float* srow = &Slds[i_l][tq * 32];
#pragma unroll
            for (int v = 0; v < 6; ++v) {
                float4 sv = ((const float4*)srow)[v];
                acc[v*4+0].x = fmaf(wv.x, sv.x, acc[v*4+0].x); acc[v*4+0].y = fmaf(wv.y, sv.x, acc[v*4+0].y);
                acc[v*4+0].z = fmaf(wv.z, sv.x, acc[v*4+0].z); acc[v*4+0].w = fmaf(wv.w, sv.x, acc[v*4+0].w);
                acc[v*4+1].x = fmaf(wv.x, sv.y, acc[v*4+1].x); acc[v*4+1].y = fmaf(wv.y, sv.y, acc[v*4+1].y);
                acc[v*4+1].z = fmaf(wv.z, sv.y, acc[v*4+1].z); acc[v*4+1].w = fmaf(wv.w, sv.y, acc[v*4+1].w);
                acc[v*4+2].x = fmaf(wv.x, sv.z, acc[v*4+2].x); acc[v*4+2].y = fmaf(wv.y, sv.z, acc[v*4+2].y);
                acc[v*4+2].z = fmaf(wv.z, sv.z, acc[v*4+2].z); acc[v*4+2].w = fmaf(wv.w, sv.z, acc[v*4+2].w);
                acc[v*4+3].x = fmaf(wv.x, sv.w, acc[v*4+3].x); acc[v*4+3].y = fmaf(wv.y, sv.w, acc[v*4+3].y);
                acc[v*4+3].z = fmaf(wv.z, sv.w, acc[v*4+3].z); acc[v*4+3].w = fmaf(wv.w, sv.w, acc[v*4+3].w);
            }
            float s24 = srow[24];
            acc[24].x = fmaf(wv.x, s24, acc[24].x); acc[24].y = fmaf(wv.y, s24, acc[24].y);
            acc[24].z = fmaf(wv.z, s24, acc[24].z); acc[24].w = fmaf(wv.w, s24, acc[24].w);
        }
    }
    __syncthreads();
    for (int r = 0; r < 4; ++r) {
        if (tq == r) {
#pragma unroll
            for (int jj = 0; jj < 4; ++jj) {
                const int ol = lane * 4 + jj;
                float m = (r == 0) ? 0.0f : m_buf[ol];
                float* orow = out + ((size_t)b * O_ + o0 + ol) * T_ + r * 25;
#pragma unroll
                for (int t = 0; t < 25; ++t) {
                    float cu = (jj == 0) ? acc[t].x : (jj == 1) ? acc[t].y
                             : (jj == 2) ? acc[t].z : acc[t].w;
                    m += cu;
                    bool f = (m > 1.0f);
                    orow[t] = f ? 1.0f : 0.0f;
                    m = f ? 0.0f : m;
                }
                m_buf[ol] = m;
            }
        }
        __syncthreads();
    }
}

extern "C" void kernel_launch(void* const* d_in, const int* in_sizes, int n_in,
                              void* d_out, int out_size, void* d_ws, size_t ws_size,
                              hipStream_t stream) {
    const float* spike  = (const float*)d_in[0];   // [128][2048][100]
    const float* weight = (const float*)d_in[1];   // [2048][2048]
    float* out = (float*)d_out;                    // [128][2048][100]

    if (ws_size < WS_NEED) {
        lif_fused_kernel<<<dim3(B_ * (O_ / TO)), dim3(256), 0, stream>>>(spike, weight, out);
        return;
    }
    unsigned short* Wt = (unsigned short*)d_ws;
    unsigned short* St = (unsigned short*)((char*)d_ws + WT_BYTES);
    unsigned* cnt = (unsigned*)((char*)d_ws + CNT_OFF);
    unsigned* wl  = (unsigned*)((char*)d_ws + WL_OFF);

    init_cnt<<<dim3(1), dim3(64), 0, stream>>>(cnt);
    prep_w<<<dim3((I_ / 64) * (O_ / 64)), dim3(256), 0, stream>>>(weight, Wt);
    prep_s<<<dim3(B_ * (I_ / 128)), dim3(256), 0, stream>>>(spike, St);
    lif_mfma3<<<dim3(B_ * (O_ / 256)), dim3(512), 0, stream>>>(Wt, St, out, cnt, wl);
    fixup<<<dim3(2048), dim3(256), 0, stream>>>(spike, weight, out, cnt, wl);
}